// Round 6
// baseline (304.546 us; speedup 1.0000x reference)
//
#include <hip/hip_runtime.h>

// B=64, K=8, H=W=128 (HW=16384). float32 in/out.
// out[0] = loss scalar; out[1..] = pred_perm (B,K,H,W) flat.
//
// Pipeline (256B memset + 2 kernels):
//   cost_kernel    : 4096 blocks x 512 thr (8 waves). Wave w handles pred row w +
//                    all 8 aug rows for one 256-float chunk: 9 independent float4
//                    loads -> ONE wait -> pure VALU -> 9-value butterfly. Last-
//                    finishing block per batch (atomic counter) reduces the 64
//                    partials and runs the Held-Karp DP -> ws_inv, ws_loss.
//   permute_kernel : pure permuted copy with aligned float4 stores; block 0 sums
//                    ws_loss -> out[0].
//
// Note: ent[j] shifts every permutation's cost equally -> argmin depends only on
// cross; ent is needed only for the loss value.

#define BB 64
#define KK 8
#define HW 16384
#define CHN 64       // chunks per batch (256 floats each)
#define EPSF 1e-15f

// ---------- compile-time mask table: all 255 nonzero 8-bit masks, level-ordered by popcount ----------
struct MaskTab {
    unsigned char masks[255];
    int off[9];
};

constexpr MaskTab make_tab() {
    MaskTab t{};
    int idx = 0;
    for (int p = 1; p <= 8; ++p) {
        t.off[p - 1] = idx;
        for (int m = 1; m < 256; ++m) {
            int c = 0;
            for (int b = 0; b < 8; ++b) c += (m >> b) & 1;
            if (c == p) t.masks[idx++] = (unsigned char)m;
        }
    }
    t.off[8] = idx;
    return t;
}

__constant__ MaskTab kTab = make_tab();

__device__ __forceinline__ float dot4(float4 t, float4 l) {
    return t.x * l.x + t.y * l.y + t.z * l.z + t.w * l.w;
}

__device__ __forceinline__ float4 log4(float4 a) {
    float4 r;
    r.x = __logf(a.x + EPSF); r.y = __logf(a.y + EPSF);
    r.z = __logf(a.z + EPSF); r.w = __logf(a.w + EPSF);
    return r;
}

// ---------- phase 1: single-round partial sums + fused per-batch DP ----------
__global__ __launch_bounds__(512) void cost_kernel(const float* __restrict__ pred,
                                                   const float* __restrict__ aug,
                                                   float* __restrict__ part,    // [4096][72]
                                                   int* __restrict__ ctr,       // [64], zeroed
                                                   int* __restrict__ ws_inv,    // [64][8] col->row
                                                   float* __restrict__ ws_loss) // [64]
{
    __shared__ float red[72];
    __shared__ float C[64];
    __shared__ float dp[256];
    __shared__ int   choice[256];
    __shared__ int   lastf;

    const int blk  = blockIdx.x;          // b*CHN + c
    const int b    = blk >> 6;
    const int c    = blk & 63;
    const int tid  = threadIdx.x;
    const int lane = tid & 63;
    const int w    = __builtin_amdgcn_readfirstlane(tid >> 6);  // wave = pred row, scalar

    const size_t base = (size_t)b * (KK * HW) + (size_t)c * 256;
    const int l4 = lane * 4;

    // --- one round of 9 independent loads ---
    const float4 pv = *(const float4*)(pred + base + (size_t)w * HW + l4);
    float4 tv[8];
#pragma unroll
    for (int j = 0; j < 8; ++j)
        tv[j] = *(const float4*)(aug + base + (size_t)j * HW + l4);

    // --- pure VALU consume ---
    const float4 lp = log4(pv);
    float acc[8];
#pragma unroll
    for (int j = 0; j < 8; ++j) acc[j] = dot4(tv[j], lp);

    float ent = 0.f;
#pragma unroll
    for (int j = 0; j < 8; ++j)
        if (j == w) ent = dot4(tv[j], log4(tv[j]));   // wave-uniform: s_cbranch skip

    // --- 9-value wave butterfly ---
#pragma unroll
    for (int v = 0; v < 8; ++v) {
        float s = acc[v];
#pragma unroll
        for (int d = 1; d < 64; d <<= 1) s += __shfl_xor(s, d);
        acc[v] = s;
    }
#pragma unroll
    for (int d = 1; d < 64; d <<= 1) ent += __shfl_xor(ent, d);

    if (lane == 0) {
        float* dst = part + (size_t)blk * 72;
#pragma unroll
        for (int j = 0; j < 8; ++j) dst[w * 8 + j] = acc[j];   // cross[i=w][j]
        dst[64 + w] = ent;                                      // ent[w]
    }

    // --- completion protocol: last block of this batch runs the DP ---
    __syncthreads();                               // all partial stores issued
    if (tid == 0) {
        __threadfence();                           // release part writes
        const int old = atomicAdd(&ctr[b], 1);     // device-scope
        lastf = (old == CHN - 1) ? 1 : 0;
    }
    __syncthreads();
    if (!lastf) return;
    __threadfence();                               // acquire other blocks' writes

    // reduce 64 chunk-partials
    if (tid < 72) {
        const float* pb = part + (size_t)(b * CHN) * 72;
        float s = 0.f;
#pragma unroll
        for (int k = 0; k < CHN; ++k) s += pb[k * 72 + tid];
        red[tid] = s;
    }
    if (tid == 0) dp[0] = 0.f;
    __syncthreads();
    if (tid < 64) C[tid] = red[64 + (tid & 7)] - red[tid];  // ent[j] - cross[i][j]
    __syncthreads();

    // Held-Karp DP over 255 masks, level-ordered; 64 mask slots per pass
    const int grp = tid >> 3;
    const int j   = tid & 7;
    for (int lvl = 1; lvl <= 8; ++lvl) {
        const int start = kTab.off[lvl - 1];
        const int end   = kTab.off[lvl];
        const float* Crow = &C[(lvl - 1) * 8];
        for (int bse = start; bse < end; bse += 64) {
            const int mi = bse + grp;
            if (mi < end) {
                const int M = kTab.masks[mi];
                float v  = 1e30f;
                int   bj = 0;
                if (M & (1 << j)) {
                    v  = dp[M ^ (1 << j)] + Crow[j];
                    bj = j;
                }
#pragma unroll
                for (int d = 1; d < 8; d <<= 1) {
                    const float ov = __shfl_xor(v, d);
                    const int   oj = __shfl_xor(bj, d);
                    if (ov < v) { v = ov; bj = oj; }
                }
                if (j == 0) { dp[M] = v; choice[M] = bj; }
            }
        }
        __syncthreads();
    }

    if (tid == 0) {
        int mask = 255;
        for (int r = 7; r >= 0; --r) {
            const int jj = choice[mask];
            ws_inv[b * 8 + jj] = r;                // column jj takes pred row r
            mask ^= 1 << jj;
        }
        ws_loss[b] = dp[255] * (1.0f / (16384.0f * 512.0f));
    }
}

// ---------- phase 2: pure permuted copy + loss finalize ----------
// grid: 2048 blocks of 256 threads; block handles quarter q=blk&3 of pair p=blk>>2.
// out+1 row base is 4B-aligned; element 3 of each row is 16B-aligned, so the middle
// 4095 quads go out as aligned float4; head 3 + tail 1 elements by one thread.
__global__ __launch_bounds__(256) void permute_kernel(const float* __restrict__ pred,
                                                      const int* __restrict__ ws_inv,
                                                      const float* __restrict__ ws_loss,
                                                      float* __restrict__ out)
{
    const int blk  = blockIdx.x;
    const int pair = blk >> 2;        // b*8 + jcol
    const int q    = blk & 3;
    const int b    = pair >> 3;
    const int tid  = threadIdx.x;

    const int src_row = ws_inv[pair]; // block-uniform scalar load
    const float* src = pred + ((size_t)(b << 3) + src_row) * HW;
    float*      drow = out + 1 + (size_t)pair * HW;

#pragma unroll
    for (int m = 0; m < 4; ++m) {
        const int f = q * 1024 + tid + 256 * m;   // quad index in [0,4096)
        const int e = 3 + 4 * f;
        if (f < 4095) {
            float4 v;
            v.x = src[e]; v.y = src[e + 1]; v.z = src[e + 2]; v.w = src[e + 3];
            *(float4*)(drow + e) = v;             // 16B-aligned
        } else {                                  // f==4095: head 3 + tail 1
            drow[0] = src[0]; drow[1] = src[1]; drow[2] = src[2];
            drow[16383] = src[16383];
        }
    }

    if (blk == 0 && tid < 64) {
        float v = ws_loss[tid];
#pragma unroll
        for (int d = 1; d < 64; d <<= 1) v += __shfl_xor(v, d);
        if (tid == 0) out[0] = v;
    }
}

extern "C" void kernel_launch(void* const* d_in, const int* in_sizes, int n_in,
                              void* d_out, int out_size, void* d_ws, size_t ws_size,
                              hipStream_t stream) {
    const float* pred = (const float*)d_in[0];
    const float* aug  = (const float*)d_in[1];
    float* out = (float*)d_out;

    int*   ctr     = (int*)d_ws;                     // 64 ints
    float* part    = (float*)d_ws + 64;              // 4096*72 floats
    int*   ws_inv  = (int*)(part + 4096 * 72);       // 512 ints
    float* ws_loss = (float*)(ws_inv + 512);         // 64 floats

    hipMemsetAsync(ctr, 0, 64 * sizeof(int), stream);

    cost_kernel<<<dim3(BB * CHN), dim3(512), 0, stream>>>(pred, aug, part, ctr, ws_inv, ws_loss);
    permute_kernel<<<dim3(2048), dim3(256), 0, stream>>>(pred, ws_inv, ws_loss, out);
}

// Round 7
// 137.312 us; speedup vs baseline: 2.2179x; 2.2179x over previous
//
#include <hip/hip_runtime.h>

// B=64, K=8, H=W=128 (HW=16384). float32 in/out.
// out[0] = loss scalar; out[1..] = pred_perm (B,K,H,W) flat.
//
// Fence-free 3-dispatch pipeline (NO memsets, NO atomics — dispatch boundaries
// provide ordering/visibility; R5/R6 showed per-block __threadfence + device
// atomics cost ~0.06-0.2 us per block and scale with block count):
//   cost_kernel    : async global->LDS staged partials of cross[i][j] and ent[j].
//   assign_kernel  : 64 blocks reduce partials + Held-Karp DP -> ws_inv, ws_loss.
//   permute_kernel : pure permuted copy, aligned float4; block 0 writes out[0].

#define BB 64
#define KK 8
#define HW 16384
#define CH 64        // chunks per batch for cost_kernel
#define CHUNK 256    // floats per chunk
#define EPSF 1e-15f

// ---------- compile-time mask table: all 255 nonzero 8-bit masks, level-ordered by popcount ----------
struct MaskTab {
    unsigned char masks[255];
    int off[9];
};

constexpr MaskTab make_tab() {
    MaskTab t{};
    int idx = 0;
    for (int p = 1; p <= 8; ++p) {
        t.off[p - 1] = idx;
        for (int m = 1; m < 256; ++m) {
            int c = 0;
            for (int b = 0; b < 8; ++b) c += (m >> b) & 1;
            if (c == p) t.masks[idx++] = (unsigned char)m;
        }
    }
    t.off[8] = idx;
    return t;
}

__constant__ MaskTab kTab = make_tab();

__device__ __forceinline__ float dot4(float4 t, float4 l) {
    return t.x * l.x + t.y * l.y + t.z * l.z + t.w * l.w;
}

__device__ __forceinline__ float4 log4(float4 a) {
    float4 r;
    r.x = __logf(a.x + EPSF); r.y = __logf(a.y + EPSF);
    r.z = __logf(a.z + EPSF); r.w = __logf(a.w + EPSF);
    return r;
}

// ---------- phase 1: partial cross/ent sums, LDS-staged (R4 structure, best measured) ----------
// grid: B*CH=4096 blocks of 256 threads (4 waves). Block stages a 256-float chunk of
// all 16 rows (pred 0-7 -> tile rows 0-7, aug 0-7 -> tile rows 8-15) via async
// global_load_lds (16B/lane, wave-uniform base + lane*16). All 16 KB is in flight
// before the single barrier; wave w then computes cross rows {2w,2w+1} and ent rows
// {2w,2w+1} from LDS. ~10 blocks/CU resident.
__global__ __launch_bounds__(256) void cost_kernel(const float* __restrict__ pred,
                                                   const float* __restrict__ aug,
                                                   float* __restrict__ part)   // [B*CH][72]
{
    __shared__ float tile[16][CHUNK];

    const int blk   = blockIdx.x;        // b*CH + chunk
    const int b     = blk >> 6;
    const int chunk = blk & 63;
    const int tid   = threadIdx.x;
    const int wave  = tid >> 6;
    const int lane  = tid & 63;

    const size_t base = (size_t)b * (KK * HW) + (size_t)chunk * CHUNK;

#pragma unroll
    for (int m = 0; m < 4; ++m) {
        const int vr = wave + 4 * m;     // virtual row 0..15, wave-uniform
        const float* g = ((vr < 8) ? (pred + base + (size_t)vr * HW)
                                   : (aug  + base + (size_t)(vr - 8) * HW)) + lane * 4;
        __builtin_amdgcn_global_load_lds(
            (const __attribute__((address_space(1))) void*)g,
            (__attribute__((address_space(3))) void*)&tile[vr][lane * 4],
            16, 0, 0);
    }
    __syncthreads();   // single vmcnt drain for the whole 16 KB

    const int w2 = 2 * wave;
    const int e4 = lane * 4;

    const float4 p0 = *(const float4*)&tile[w2][e4];
    const float4 p1 = *(const float4*)&tile[w2 + 1][e4];
    const float4 la = log4(p0);
    const float4 lc = log4(p1);
    const float4 t0 = *(const float4*)&tile[8 + w2][e4];
    const float4 t1 = *(const float4*)&tile[8 + w2 + 1][e4];
    float e0 = dot4(t0, log4(t0));
    float e1 = dot4(t1, log4(t1));

    float acc[16];
#pragma unroll
    for (int j = 0; j < 8; ++j) {
        const float4 tv = *(const float4*)&tile[8 + j][e4];
        acc[j]     = dot4(tv, la);
        acc[8 + j] = dot4(tv, lc);
    }

    // wave-wide butterfly reduce: 18 values
#pragma unroll
    for (int v = 0; v < 16; ++v) {
        float s = acc[v];
#pragma unroll
        for (int d = 1; d < 64; d <<= 1) s += __shfl_xor(s, d);
        acc[v] = s;
    }
#pragma unroll
    for (int d = 1; d < 64; d <<= 1) e0 += __shfl_xor(e0, d);
#pragma unroll
    for (int d = 1; d < 64; d <<= 1) e1 += __shfl_xor(e1, d);

    if (lane == 0) {
        float* dst = part + (size_t)blk * 72;
#pragma unroll
        for (int j = 0; j < 8; ++j) {
            dst[16 * wave + j]     = acc[j];       // cross[i=2w][j]
            dst[16 * wave + 8 + j] = acc[8 + j];   // cross[i=2w+1][j]
        }
        dst[64 + w2]     = e0;                     // ent[2w]
        dst[64 + w2 + 1] = e1;                     // ent[2w+1]
    }
}

// ---------- phase 2: reduce partials + Held-Karp DP per batch ----------
// grid: B=64 blocks of 64 threads (1 wave). Dispatch boundary guarantees part[]
// visibility — no fences needed.
__global__ __launch_bounds__(64) void assign_kernel(const float* __restrict__ part,
                                                    int* __restrict__ ws_inv,     // [B][8]: col -> src row
                                                    float* __restrict__ ws_loss)  // [B]
{
    __shared__ float C[64];     // C[i*8+j] = ent[j] - cross[i][j] (unscaled)
    __shared__ float dp[256];
    __shared__ int   choice[256];

    const int b    = blockIdx.x;
    const int lane = threadIdx.x;
    const float* pb = part + (size_t)b * CH * 72;

    float s = 0.f;
#pragma unroll 8
    for (int c = 0; c < CH; ++c) s += pb[c * 72 + lane];
    float e = 0.f;
    if (lane < 8) {
#pragma unroll 8
        for (int c = 0; c < CH; ++c) e += pb[c * 72 + 64 + lane];
    }
    const float entj = __shfl(e, lane & 7);   // ent[j] from lane j
    C[lane] = entj - s;
    if (lane == 0) dp[0] = 0.f;
    __syncthreads();

    const int grp = lane >> 3;
    const int j   = lane & 7;

    for (int p = 1; p <= 8; ++p) {
        const int start = kTab.off[p - 1];
        const int end   = kTab.off[p];
        const float* Crow = &C[(p - 1) * 8];
        for (int base = start; base < end; base += 8) {
            const int mi = base + grp;
            if (mi < end) {
                const int M = kTab.masks[mi];
                float v  = 1e30f;
                int   bj = 0;
                if (M & (1 << j)) {
                    v  = dp[M ^ (1 << j)] + Crow[j];
                    bj = j;
                }
#pragma unroll
                for (int d = 1; d < 8; d <<= 1) {
                    const float ov = __shfl_xor(v, d);
                    const int   oj = __shfl_xor(bj, d);
                    if (ov < v) { v = ov; bj = oj; }
                }
                if (j == 0) { dp[M] = v; choice[M] = bj; }
            }
        }
        __syncthreads();
    }

    if (lane == 0) {
        int mask = 255;
        for (int r = 7; r >= 0; --r) {
            const int jj = choice[mask];
            ws_inv[b * 8 + jj] = r;        // column jj takes pred row r
            mask ^= 1 << jj;
        }
        ws_loss[b] = dp[255] * (1.0f / (16384.0f * 512.0f));
    }
}

// ---------- phase 3: pure permuted copy + loss finalize ----------
// grid: 2048 blocks of 256 threads; block handles quarter q=blk&3 of pair p=blk>>2.
// out+1 row base is 4B-aligned; element 3 of each row is 16B-aligned, so the middle
// 4095 quads go out as aligned float4; head 3 + tail 1 elements by one thread.
// Block 0 also sums ws_loss -> out[0] (single writer, no atomic, no memset).
__global__ __launch_bounds__(256) void permute_kernel(const float* __restrict__ pred,
                                                      const int* __restrict__ ws_inv,
                                                      const float* __restrict__ ws_loss,
                                                      float* __restrict__ out)
{
    const int blk  = blockIdx.x;
    const int pair = blk >> 2;        // b*8 + jcol
    const int q    = blk & 3;
    const int b    = pair >> 3;
    const int tid  = threadIdx.x;

    const int src_row = ws_inv[pair]; // block-uniform scalar load
    const float* src = pred + ((size_t)(b << 3) + src_row) * HW;
    float*      drow = out + 1 + (size_t)pair * HW;

#pragma unroll
    for (int m = 0; m < 4; ++m) {
        const int f = q * 1024 + tid + 256 * m;   // quad index in [0,4096)
        const int e = 3 + 4 * f;
        if (f < 4095) {
            float4 v;
            v.x = src[e]; v.y = src[e + 1]; v.z = src[e + 2]; v.w = src[e + 3];
            *(float4*)(drow + e) = v;             // 16B-aligned
        } else {                                  // f==4095: head 3 + tail 1
            drow[0] = src[0]; drow[1] = src[1]; drow[2] = src[2];
            drow[16383] = src[16383];
        }
    }

    if (blk == 0 && tid < 64) {
        float v = ws_loss[tid];
#pragma unroll
        for (int d = 1; d < 64; d <<= 1) v += __shfl_xor(v, d);
        if (tid == 0) out[0] = v;
    }
}

extern "C" void kernel_launch(void* const* d_in, const int* in_sizes, int n_in,
                              void* d_out, int out_size, void* d_ws, size_t ws_size,
                              hipStream_t stream) {
    const float* pred = (const float*)d_in[0];
    const float* aug  = (const float*)d_in[1];
    float* out = (float*)d_out;

    float* part    = (float*)d_ws;                   // 4096*72 floats
    int*   ws_inv  = (int*)(part + BB * CH * 72);    // 512 ints
    float* ws_loss = (float*)(ws_inv + BB * KK);     // 64 floats

    cost_kernel<<<dim3(BB * CH), dim3(256), 0, stream>>>(pred, aug, part);
    assign_kernel<<<dim3(BB), dim3(64), 0, stream>>>(part, ws_inv, ws_loss);
    permute_kernel<<<dim3(2048), dim3(256), 0, stream>>>(pred, ws_inv, ws_loss, out);
}

// Round 8
// 123.146 us; speedup vs baseline: 2.4731x; 1.1150x over previous
//
#include <hip/hip_runtime.h>

// B=64, K=8, H=W=128 (HW=16384). float32 in/out.
// out[0] = loss scalar; out[1..] = pred_perm (B,K,H,W) flat.
//
// Fence-free 2-dispatch pipeline (no memsets, no extra launches):
//   cost_kernel    : 1024 blocks; double-buffered global_load_lds staging; partial
//                    cross[i][j]/ent[j] sums; ONE 18-value butterfly per block
//                    (DS-pipe pressure 4x lower than the 4096-block variant).
//                    Block 0 zeroes out[0] for the loss atomics.
//   permute_kernel : fused Held-Karp DP (redundant per block, parallel) + permuted
//                    copy with aligned float4 stores; one block per batch
//                    atomicAdds the batch loss into out[0].

#define BB 64
#define KK 8
#define HW 16384
#define SPANS 16     // cost blocks per batch
#define SPAN 1024    // floats per span per row
#define NCH 4        // 256-float chunks per span
#define CHUNK 256
#define EPSF 1e-15f

// ---------- compile-time mask table: all 255 nonzero 8-bit masks, level-ordered by popcount ----------
struct MaskTab {
    unsigned char masks[255];
    int off[9];
};

constexpr MaskTab make_tab() {
    MaskTab t{};
    int idx = 0;
    for (int p = 1; p <= 8; ++p) {
        t.off[p - 1] = idx;
        for (int m = 1; m < 256; ++m) {
            int c = 0;
            for (int b = 0; b < 8; ++b) c += (m >> b) & 1;
            if (c == p) t.masks[idx++] = (unsigned char)m;
        }
    }
    t.off[8] = idx;
    return t;
}

__constant__ MaskTab kTab = make_tab();

__device__ __forceinline__ float dot4(float4 t, float4 l) {
    return t.x * l.x + t.y * l.y + t.z * l.z + t.w * l.w;
}

__device__ __forceinline__ float4 log4(float4 a) {
    float4 r;
    r.x = __logf(a.x + EPSF); r.y = __logf(a.y + EPSF);
    r.z = __logf(a.z + EPSF); r.w = __logf(a.w + EPSF);
    return r;
}

// ---------- phase 1: partial cross/ent sums, double-buffered LDS staging ----------
// grid: B*SPANS=1024 blocks of 256 threads (4 waves). Block covers a 1024-float span
// of all 16 rows in 4 chunks of 256. stage(c+1) is issued right AFTER the barrier
// that drained stage(c), so it overlaps compute(c) (different LDS buffer). Wave w
// computes cross rows {2w,2w+1}; ent rows come from the same aug LDS reads via
// wave-uniform branches. One 18-value butterfly per wave at the end.
__global__ __launch_bounds__(256) void cost_kernel(const float* __restrict__ pred,
                                                   const float* __restrict__ aug,
                                                   float* __restrict__ part,   // [1024][72]
                                                   float* __restrict__ out)
{
    __shared__ float tile[2][16][CHUNK];

    const int blk  = blockIdx.x;        // b*SPANS + s
    const int b    = blk >> 4;
    const int s    = blk & 15;
    const int tid  = threadIdx.x;
    const int wave = tid >> 6;
    const int lane = tid & 63;

    if (blk == 0 && tid == 0) out[0] = 0.f;   // loss accumulator init (pre-atomics)

    const size_t base = (size_t)b * (KK * HW) + (size_t)s * SPAN;
    const int e4 = lane * 4;
    const int w2 = 2 * wave;

    // async-stage chunk c of all 16 rows into tile[c&1]; wave w stages rows {w,w+4,w+8,w+12}
#define STAGE(c)                                                                          \
    {                                                                                     \
        const int pb_ = (c) & 1;                                                          \
        _Pragma("unroll")                                                                 \
        for (int m = 0; m < 4; ++m) {                                                     \
            const int vr = wave + 4 * m;                                                  \
            const float* g = ((vr < 8) ? (pred + base + (size_t)vr * HW)                  \
                                       : (aug + base + (size_t)(vr - 8) * HW))            \
                             + (c) * CHUNK + e4;                                          \
            __builtin_amdgcn_global_load_lds(                                             \
                (const __attribute__((address_space(1))) void*)g,                         \
                (__attribute__((address_space(3))) void*)&tile[pb_][vr][e4], 16, 0, 0);   \
        }                                                                                 \
    }

    STAGE(0)

    float acc[16];
#pragma unroll
    for (int v = 0; v < 16; ++v) acc[v] = 0.f;
    float e0 = 0.f, e1 = 0.f;

#pragma unroll
    for (int c = 0; c < NCH; ++c) {
        __syncthreads();                 // drains vmcnt: stage(c) landed; prev compute done
        if (c + 1 < NCH) STAGE(c + 1)    // fire async into the other buffer, overlaps compute

        const int pb = c & 1;
        const float4 la = log4(*(const float4*)&tile[pb][w2][e4]);
        const float4 lc = log4(*(const float4*)&tile[pb][w2 + 1][e4]);
#pragma unroll
        for (int j = 0; j < 8; ++j) {
            const float4 tv = *(const float4*)&tile[pb][8 + j][e4];
            acc[j]     += dot4(tv, la);
            acc[8 + j] += dot4(tv, lc);
            if (j == w2)     e0 += dot4(tv, log4(tv));   // wave-uniform branch
            if (j == w2 + 1) e1 += dot4(tv, log4(tv));
        }
    }
#undef STAGE

    // one 18-value wave butterfly per block
#pragma unroll
    for (int v = 0; v < 16; ++v) {
        float sv = acc[v];
#pragma unroll
        for (int d = 1; d < 64; d <<= 1) sv += __shfl_xor(sv, d);
        acc[v] = sv;
    }
#pragma unroll
    for (int d = 1; d < 64; d <<= 1) e0 += __shfl_xor(e0, d);
#pragma unroll
    for (int d = 1; d < 64; d <<= 1) e1 += __shfl_xor(e1, d);

    if (lane == 0) {
        float* dst = part + (size_t)blk * 72;
#pragma unroll
        for (int j = 0; j < 8; ++j) {
            dst[16 * wave + j]     = acc[j];       // cross[i=2w][j]
            dst[16 * wave + 8 + j] = acc[8 + j];   // cross[i=2w+1][j]
        }
        dst[64 + w2]     = e0;                     // ent[2w]
        dst[64 + w2 + 1] = e1;                     // ent[2w+1]
    }
}

// ---------- phase 2: fused DP + permuted copy ----------
// grid: 1024 blocks of 256 threads; block g handles half (g&1) of pair p=g>>1.
// Every block redundantly reduces its batch's 16 span-partials and runs the
// Held-Karp DP (parallel, ~1-2 us). Block g==16b atomicAdds the batch loss.
// Stores: out+1 row base is 4B-aligned; element 3 of each row is 16B-aligned ->
// middle 4095 quads as aligned float4; head 3 + tail 1 scalar by one thread.
__global__ __launch_bounds__(256) void permute_kernel(const float* __restrict__ pred,
                                                      const float* __restrict__ part,
                                                      float* __restrict__ out)
{
    __shared__ float red[72];
    __shared__ float C[64];     // C[i*8+j] = ent[j] - cross[i][j] (unscaled)
    __shared__ float dp[256];
    __shared__ int   choice[256];
    __shared__ int   inv8[8];   // col -> src row

    const int g    = blockIdx.x;
    const int p    = g >> 1;       // pair = b*8 + jcol
    const int half = g & 1;
    const int b    = p >> 3;
    const int tid  = threadIdx.x;

    // --- reduce the 16 span-partials for batch b ---
    const float* pb = part + (size_t)b * SPANS * 72;
    if (tid < 72) {
        float s = 0.f;
#pragma unroll
        for (int c = 0; c < SPANS; ++c) s += pb[c * 72 + tid];
        red[tid] = s;
    }
    if (tid == 0) dp[0] = 0.f;
    __syncthreads();
    if (tid < 64) C[tid] = red[64 + (tid & 7)] - red[tid];
    __syncthreads();

    // --- Held-Karp DP over 255 masks, level-ordered; 32 mask slots per pass ---
    const int grp = tid >> 3;
    const int j   = tid & 7;
    for (int lvl = 1; lvl <= 8; ++lvl) {
        const int start = kTab.off[lvl - 1];
        const int end   = kTab.off[lvl];
        const float* Crow = &C[(lvl - 1) * 8];
        for (int bse = start; bse < end; bse += 32) {
            const int mi = bse + grp;
            if (mi < end) {
                const int M = kTab.masks[mi];
                float v  = 1e30f;
                int   bj = 0;
                if (M & (1 << j)) {
                    v  = dp[M ^ (1 << j)] + Crow[j];
                    bj = j;
                }
#pragma unroll
                for (int d = 1; d < 8; d <<= 1) {
                    const float ov = __shfl_xor(v, d);
                    const int   oj = __shfl_xor(bj, d);
                    if (ov < v) { v = ov; bj = oj; }
                }
                if (j == 0) { dp[M] = v; choice[M] = bj; }
            }
        }
        __syncthreads();
    }

    if (tid == 0) {
        int mask = 255;
        for (int r = 7; r >= 0; --r) {
            const int jj = choice[mask];
            inv8[jj] = r;              // column jj takes pred row r
            mask ^= 1 << jj;
        }
        if (g == (b << 4))             // one designated block per batch
            atomicAdd(out, dp[255] * (1.0f / (16384.0f * 512.0f)));
    }
    __syncthreads();

    // --- permuted copy of half a row (8192 elements = 2048 quads) ---
    const int src_row = inv8[p & 7];   // uniform per block
    const float* src  = pred + ((size_t)(b << 3) + src_row) * HW;
    float*      drow  = out + 1 + (size_t)p * HW;

#pragma unroll
    for (int m = 0; m < 8; ++m) {
        const int f = half * 2048 + tid + 256 * m;   // quad index in [0,4096)
        const int e = 3 + 4 * f;
        if (f < 4095) {
            float4 v;
            v.x = src[e]; v.y = src[e + 1]; v.z = src[e + 2]; v.w = src[e + 3];
            *(float4*)(drow + e) = v;                // 16B-aligned
        } else {                                     // f==4095: head 3 + tail 1
            drow[0] = src[0]; drow[1] = src[1]; drow[2] = src[2];
            drow[16383] = src[16383];
        }
    }
}

extern "C" void kernel_launch(void* const* d_in, const int* in_sizes, int n_in,
                              void* d_out, int out_size, void* d_ws, size_t ws_size,
                              hipStream_t stream) {
    const float* pred = (const float*)d_in[0];
    const float* aug  = (const float*)d_in[1];
    float* out = (float*)d_out;
    float* part = (float*)d_ws;                      // 1024*72 floats

    cost_kernel<<<dim3(BB * SPANS), dim3(256), 0, stream>>>(pred, aug, part, out);
    permute_kernel<<<dim3(1024), dim3(256), 0, stream>>>(pred, part, out);
}

// Round 9
// 121.627 us; speedup vs baseline: 2.5039x; 1.0125x over previous
//
#include <hip/hip_runtime.h>

// B=64, K=8, H=W=128 (HW=16384). float32 in/out.
// out[0] = loss scalar; out[1..] = pred_perm (B,K,H,W) flat.
//
// Fence-free 2-dispatch pipeline (no memsets, no extra launches):
//   cost_kernel    : 1024 blocks; double-buffered global_load_lds staging; partial
//                    cross[i][j]/ent[j] sums; ONE 18-value butterfly per wave.
//                    Block 0 zeroes out[0] for the loss atomics. (R8-identical —
//                    best measured across 8 structural variants, ~38 us plateau.)
//   permute_kernel : 512 blocks (full row each): fused Held-Karp DP (redundant per
//                    block, parallel) + permuted copy with aligned float4 stores;
//                    one block per batch atomicAdds the batch loss into out[0].

#define BB 64
#define KK 8
#define HW 16384
#define SPANS 16     // cost blocks per batch
#define SPAN 1024    // floats per span per row
#define NCH 4        // 256-float chunks per span
#define CHUNK 256
#define EPSF 1e-15f

// ---------- compile-time mask table: all 255 nonzero 8-bit masks, level-ordered by popcount ----------
struct MaskTab {
    unsigned char masks[255];
    int off[9];
};

constexpr MaskTab make_tab() {
    MaskTab t{};
    int idx = 0;
    for (int p = 1; p <= 8; ++p) {
        t.off[p - 1] = idx;
        for (int m = 1; m < 256; ++m) {
            int c = 0;
            for (int b = 0; b < 8; ++b) c += (m >> b) & 1;
            if (c == p) t.masks[idx++] = (unsigned char)m;
        }
    }
    t.off[8] = idx;
    return t;
}

__constant__ MaskTab kTab = make_tab();

__device__ __forceinline__ float dot4(float4 t, float4 l) {
    return t.x * l.x + t.y * l.y + t.z * l.z + t.w * l.w;
}

__device__ __forceinline__ float4 log4(float4 a) {
    float4 r;
    r.x = __logf(a.x + EPSF); r.y = __logf(a.y + EPSF);
    r.z = __logf(a.z + EPSF); r.w = __logf(a.w + EPSF);
    return r;
}

// ---------- phase 1: partial cross/ent sums, double-buffered LDS staging ----------
__global__ __launch_bounds__(256) void cost_kernel(const float* __restrict__ pred,
                                                   const float* __restrict__ aug,
                                                   float* __restrict__ part,   // [1024][72]
                                                   float* __restrict__ out)
{
    __shared__ float tile[2][16][CHUNK];

    const int blk  = blockIdx.x;        // b*SPANS + s
    const int b    = blk >> 4;
    const int s    = blk & 15;
    const int tid  = threadIdx.x;
    const int wave = tid >> 6;
    const int lane = tid & 63;

    if (blk == 0 && tid == 0) out[0] = 0.f;   // loss accumulator init (pre-atomics)

    const size_t base = (size_t)b * (KK * HW) + (size_t)s * SPAN;
    const int e4 = lane * 4;
    const int w2 = 2 * wave;

#define STAGE(c)                                                                          \
    {                                                                                     \
        const int pb_ = (c) & 1;                                                          \
        _Pragma("unroll")                                                                 \
        for (int m = 0; m < 4; ++m) {                                                     \
            const int vr = wave + 4 * m;                                                  \
            const float* g = ((vr < 8) ? (pred + base + (size_t)vr * HW)                  \
                                       : (aug + base + (size_t)(vr - 8) * HW))            \
                             + (c) * CHUNK + e4;                                          \
            __builtin_amdgcn_global_load_lds(                                             \
                (const __attribute__((address_space(1))) void*)g,                         \
                (__attribute__((address_space(3))) void*)&tile[pb_][vr][e4], 16, 0, 0);   \
        }                                                                                 \
    }

    STAGE(0)

    float acc[16];
#pragma unroll
    for (int v = 0; v < 16; ++v) acc[v] = 0.f;
    float e0 = 0.f, e1 = 0.f;

#pragma unroll
    for (int c = 0; c < NCH; ++c) {
        __syncthreads();                 // drains vmcnt: stage(c) landed
        if (c + 1 < NCH) STAGE(c + 1)    // async into the other buffer, overlaps compute

        const int pb = c & 1;
        const float4 la = log4(*(const float4*)&tile[pb][w2][e4]);
        const float4 lc = log4(*(const float4*)&tile[pb][w2 + 1][e4]);
#pragma unroll
        for (int j = 0; j < 8; ++j) {
            const float4 tv = *(const float4*)&tile[pb][8 + j][e4];
            acc[j]     += dot4(tv, la);
            acc[8 + j] += dot4(tv, lc);
            if (j == w2)     e0 += dot4(tv, log4(tv));   // wave-uniform branch
            if (j == w2 + 1) e1 += dot4(tv, log4(tv));
        }
    }
#undef STAGE

    // one 18-value wave butterfly per wave
#pragma unroll
    for (int v = 0; v < 16; ++v) {
        float sv = acc[v];
#pragma unroll
        for (int d = 1; d < 64; d <<= 1) sv += __shfl_xor(sv, d);
        acc[v] = sv;
    }
#pragma unroll
    for (int d = 1; d < 64; d <<= 1) e0 += __shfl_xor(e0, d);
#pragma unroll
    for (int d = 1; d < 64; d <<= 1) e1 += __shfl_xor(e1, d);

    if (lane == 0) {
        float* dst = part + (size_t)blk * 72;
#pragma unroll
        for (int j = 0; j < 8; ++j) {
            dst[16 * wave + j]     = acc[j];       // cross[i=2w][j]
            dst[16 * wave + 8 + j] = acc[8 + j];   // cross[i=2w+1][j]
        }
        dst[64 + w2]     = e0;                     // ent[2w]
        dst[64 + w2 + 1] = e1;                     // ent[2w+1]
    }
}

// ---------- phase 2: fused DP + permuted copy (512 blocks, full row each) ----------
// grid: 512 blocks of 256 threads; block p handles pair p = b*8 + jcol (one full
// 16384-float row). Each block redundantly reduces its batch's 16 span-partials and
// runs the Held-Karp DP (~parallel). Block p==b*8 atomicAdds the batch loss.
// Stores: out+1 row base is 4B-aligned; element 3 of each row is 16B-aligned ->
// middle 4095 quads as aligned float4; head 3 + tail 1 scalar by one thread.
__global__ __launch_bounds__(256) void permute_kernel(const float* __restrict__ pred,
                                                      const float* __restrict__ part,
                                                      float* __restrict__ out)
{
    __shared__ float red[72];
    __shared__ float C[64];     // C[i*8+j] = ent[j] - cross[i][j] (unscaled)
    __shared__ float dp[256];
    __shared__ int   choice[256];
    __shared__ int   inv8[8];   // col -> src row

    const int p    = blockIdx.x;   // pair = b*8 + jcol
    const int b    = p >> 3;
    const int tid  = threadIdx.x;

    // --- reduce the 16 span-partials for batch b ---
    const float* pb = part + (size_t)b * SPANS * 72;
    if (tid < 72) {
        float s = 0.f;
#pragma unroll
        for (int c = 0; c < SPANS; ++c) s += pb[c * 72 + tid];
        red[tid] = s;
    }
    if (tid == 0) dp[0] = 0.f;
    __syncthreads();
    if (tid < 64) C[tid] = red[64 + (tid & 7)] - red[tid];
    __syncthreads();

    // --- Held-Karp DP over 255 masks, level-ordered; 32 mask slots per pass ---
    const int grp = tid >> 3;
    const int j   = tid & 7;
    for (int lvl = 1; lvl <= 8; ++lvl) {
        const int start = kTab.off[lvl - 1];
        const int end   = kTab.off[lvl];
        const float* Crow = &C[(lvl - 1) * 8];
        for (int bse = start; bse < end; bse += 32) {
            const int mi = bse + grp;
            if (mi < end) {
                const int M = kTab.masks[mi];
                float v  = 1e30f;
                int   bj = 0;
                if (M & (1 << j)) {
                    v  = dp[M ^ (1 << j)] + Crow[j];
                    bj = j;
                }
#pragma unroll
                for (int d = 1; d < 8; d <<= 1) {
                    const float ov = __shfl_xor(v, d);
                    const int   oj = __shfl_xor(bj, d);
                    if (ov < v) { v = ov; bj = oj; }
                }
                if (j == 0) { dp[M] = v; choice[M] = bj; }
            }
        }
        __syncthreads();
    }

    if (tid == 0) {
        int mask = 255;
        for (int r = 7; r >= 0; --r) {
            const int jj = choice[mask];
            inv8[jj] = r;              // column jj takes pred row r
            mask ^= 1 << jj;
        }
        if ((p & 7) == 0)              // one designated block per batch
            atomicAdd(out, dp[255] * (1.0f / (16384.0f * 512.0f)));
    }
    __syncthreads();

    // --- permuted copy of the full row (16384 elements = 4096 quads) ---
    const int src_row = inv8[p & 7];   // uniform per block
    const float* src  = pred + ((size_t)(b << 3) + src_row) * HW;
    float*      drow  = out + 1 + (size_t)p * HW;

#pragma unroll
    for (int m = 0; m < 16; ++m) {
        const int f = tid + 256 * m;              // quad index in [0,4096)
        const int e = 3 + 4 * f;
        if (f < 4095) {
            float4 v;
            v.x = src[e]; v.y = src[e + 1]; v.z = src[e + 2]; v.w = src[e + 3];
            *(float4*)(drow + e) = v;             // 16B-aligned
        } else {                                  // f==4095: head 3 + tail 1
            drow[0] = src[0]; drow[1] = src[1]; drow[2] = src[2];
            drow[16383] = src[16383];
        }
    }
}

extern "C" void kernel_launch(void* const* d_in, const int* in_sizes, int n_in,
                              void* d_out, int out_size, void* d_ws, size_t ws_size,
                              hipStream_t stream) {
    const float* pred = (const float*)d_in[0];
    const float* aug  = (const float*)d_in[1];
    float* out = (float*)d_out;
    float* part = (float*)d_ws;                      // 1024*72 floats

    cost_kernel<<<dim3(BB * SPANS), dim3(256), 0, stream>>>(pred, aug, part, out);
    permute_kernel<<<dim3(512), dim3(256), 0, stream>>>(pred, part, out);
}